// Round 13
// baseline (646.655 us; speedup 1.0000x reference)
//
#include <hip/hip_runtime.h>
#include <hip/hip_bf16.h>
#include <cstdint>
#include <cstddef>

#define D_NODE 128
#define D_EDGE 64
#define D_HID  128

typedef __attribute__((ext_vector_type(8))) short bf16x8;
typedef __attribute__((ext_vector_type(4))) float f32x4;

__device__ __forceinline__ float silu_f(float x) {
  return x * __builtin_amdgcn_rcpf(1.f + __expf(-x));
}

__device__ __forceinline__ short f2bf(float f) {
  union { float f; uint32_t u; } v; v.f = f;
  uint32_t r = v.u + 0x7fff + ((v.u >> 16) & 1);  // RNE
  return (short)(r >> 16);
}

__device__ __forceinline__ float bf2f(uint32_t lo16) {
  union { uint32_t u; float f; } v; v.u = lo16 << 16; return v.f;
}

__device__ __forceinline__ uint32_t packkv(float k, float v) {
  return (uint32_t)(uint16_t)f2bf(k) | ((uint32_t)(uint16_t)f2bf(v) << 16);
}

// ------------- prep: repack W1/W2 into bf16 MFMA B-fragment order ----------
__global__ void prep_weights(const float* __restrict__ W1, const float* __restrict__ W2,
                             short* __restrict__ W1f, short* __restrict__ W2f) {
  const int idx = blockIdx.x * 256 + threadIdx.x;   // 2048 threads
  if (idx < 1024) {
    const int frag = idx >> 6, lane = idx & 63;
    const int kk = frag >> 3, n = frag & 7;
    const int lg = lane >> 4, lr = lane & 15;
#pragma unroll
    for (int j = 0; j < 8; ++j) {
      const int k = kk * 32 + lg * 8 + j;
      W1f[idx * 8 + j] = f2bf(W1[k * 128 + n * 16 + lr]);
    }
  } else if (idx < 2048) {
    const int t = idx - 1024;
    const int frag = t >> 6, lane = t & 63;
    const int kk = frag >> 2, n = frag & 3;
    const int lg = lane >> 4, lr = lane & 15;
#pragma unroll
    for (int j = 0; j < 8; ++j) {
      const int k = kk * 32 + lg * 8 + j;
      W2f[t * 8 + j] = f2bf(W2[k * 64 + n * 16 + lr]);
    }
  }
}

// ------------- edge MLP via MFMA, zero barriers (unchanged) ----------------
__global__ __launch_bounds__(256) void edge_mlp_mfma(
    const float* __restrict__ ef, const short* __restrict__ W1f,
    const float* __restrict__ b1, const short* __restrict__ W2f,
    const float* __restrict__ b2, float* __restrict__ out, int E) {
  __shared__ short Hs[128 * 136];

  const int tid = threadIdx.x;
  const int e0 = blockIdx.x * 128;
  const int lane = tid & 63, wave = tid >> 6;
  const int r0 = wave * 32;
  const int lr = lane & 15, lg = lane >> 4;

  float b1v[8], b2v[4];
#pragma unroll
  for (int n = 0; n < 8; ++n) b1v[n] = b1[n * 16 + lr];
#pragma unroll
  for (int n = 0; n < 4; ++n) b2v[n] = b2[n * 16 + lr];

  // ---- GEMM1: [32 rows/wave x 128] = X(32x64) @ W1(64x128) ----
  f32x4 acc1[2][8];
#pragma unroll
  for (int m = 0; m < 2; ++m)
#pragma unroll
    for (int n = 0; n < 8; ++n) acc1[m][n] = (f32x4){0.f, 0.f, 0.f, 0.f};

#pragma unroll
  for (int kk = 0; kk < 2; ++kk) {
    bf16x8 a[2];
#pragma unroll
    for (int m = 0; m < 2; ++m) {
      const int row = e0 + r0 + m * 16 + lr;
      const float* __restrict__ xp = ef + (size_t)row * 64 + kk * 32 + lg * 8;
      float4 f0 = make_float4(0.f, 0.f, 0.f, 0.f), f1 = f0;
      if (row < E) {
        f0 = *reinterpret_cast<const float4*>(xp);
        f1 = *reinterpret_cast<const float4*>(xp + 4);
      }
      a[m][0] = f2bf(f0.x); a[m][1] = f2bf(f0.y); a[m][2] = f2bf(f0.z); a[m][3] = f2bf(f0.w);
      a[m][4] = f2bf(f1.x); a[m][5] = f2bf(f1.y); a[m][6] = f2bf(f1.z); a[m][7] = f2bf(f1.w);
    }
#pragma unroll
    for (int n = 0; n < 8; ++n) {
      const bf16x8 b = *reinterpret_cast<const bf16x8*>(W1f + (((kk << 3) + n) << 9) + (lane << 3));
      acc1[0][n] = __builtin_amdgcn_mfma_f32_16x16x32_bf16(a[0], b, acc1[0][n], 0, 0, 0);
      acc1[1][n] = __builtin_amdgcn_mfma_f32_16x16x32_bf16(a[1], b, acc1[1][n], 0, 0, 0);
    }
  }

  // ---- H = silu(acc1+b1) -> LDS ----
#pragma unroll
  for (int m = 0; m < 2; ++m)
#pragma unroll
    for (int n = 0; n < 8; ++n)
#pragma unroll
      for (int r = 0; r < 4; ++r) {
        const float hv = silu_f(acc1[m][n][r] + b1v[n]);
        Hs[(r0 + m * 16 + lg * 4 + r) * 136 + n * 16 + lr] = f2bf(hv);
      }
  // no barrier: each wave reads back only rows r0..r0+31 (its own writes)

  // ---- GEMM2: [32 x 64] = H(32x128) @ W2(128x64) ----
  f32x4 acc2[2][4];
#pragma unroll
  for (int m = 0; m < 2; ++m)
#pragma unroll
    for (int n = 0; n < 4; ++n) acc2[m][n] = (f32x4){0.f, 0.f, 0.f, 0.f};
#pragma unroll
  for (int kk = 0; kk < 4; ++kk) {
    const bf16x8 a0 = *reinterpret_cast<const bf16x8*>(&Hs[(r0 + lr) * 136 + kk * 32 + lg * 8]);
    const bf16x8 a1 = *reinterpret_cast<const bf16x8*>(&Hs[(r0 + 16 + lr) * 136 + kk * 32 + lg * 8]);
#pragma unroll
    for (int n = 0; n < 4; ++n) {
      const bf16x8 b = *reinterpret_cast<const bf16x8*>(W2f + (((kk << 2) + n) << 9) + (lane << 3));
      acc2[0][n] = __builtin_amdgcn_mfma_f32_16x16x32_bf16(a0, b, acc2[0][n], 0, 0, 0);
      acc2[1][n] = __builtin_amdgcn_mfma_f32_16x16x32_bf16(a1, b, acc2[1][n], 0, 0, 0);
    }
  }
#pragma unroll
  for (int m = 0; m < 2; ++m)
#pragma unroll
    for (int r = 0; r < 4; ++r) {
      const int row = r0 + m * 16 + lg * 4 + r;
      if (e0 + row < E) {
        float* __restrict__ op = out + (size_t)(e0 + row) * 64;
#pragma unroll
        for (int n = 0; n < 4; ++n) op[n * 16 + lr] = silu_f(acc2[m][n][r] + b2v[n]);
      }
    }
}

// ---------------- QKV projection: Q fp32 pre-scaled, K/V packed bf16 -------
__global__ __launch_bounds__(256) void qkv_kernel(
    const float* __restrict__ nf, const float* __restrict__ Wq,
    const float* __restrict__ Wk, const float* __restrict__ Wv,
    float* __restrict__ Q, uint32_t* __restrict__ KV, int N) {
  __shared__ float xs[32][D_NODE];
  const int tid = threadIdx.x;
  const int node0 = blockIdx.x * 32;
  const int nrows = min(32, N - node0);
  for (int i = tid; i < nrows * 32; i += 256) {
    const int r = i >> 5, c = (i & 31) * 4;
    float4 v = *reinterpret_cast<const float4*>(nf + (size_t)(node0 + r) * D_NODE + c);
    xs[r][c] = v.x; xs[r][c + 1] = v.y; xs[r][c + 2] = v.z; xs[r][c + 3] = v.w;
  }
  __syncthreads();
  const int wave = tid >> 6, lane = tid & 63;
  const int nn0 = wave * 8;
  float aq[8][2] = {}, ak[8][2] = {}, av[8][2] = {};
  for (int k = 0; k < D_NODE; ++k) {
    const float wq0 = Wq[(k << 7) + lane], wq1 = Wq[(k << 7) + 64 + lane];
    const float wk0 = Wk[(k << 7) + lane], wk1 = Wk[(k << 7) + 64 + lane];
    const float wv0 = Wv[(k << 7) + lane], wv1 = Wv[(k << 7) + 64 + lane];
#pragma unroll
    for (int nn = 0; nn < 8; ++nn) {
      const float x = xs[nn0 + nn][k];
      aq[nn][0] = fmaf(x, wq0, aq[nn][0]); aq[nn][1] = fmaf(x, wq1, aq[nn][1]);
      ak[nn][0] = fmaf(x, wk0, ak[nn][0]); ak[nn][1] = fmaf(x, wk1, ak[nn][1]);
      av[nn][0] = fmaf(x, wv0, av[nn][0]); av[nn][1] = fmaf(x, wv1, av[nn][1]);
    }
  }
  const float scale = 0.088388347648318447f;  // 1/sqrt(128), folded into Q
#pragma unroll
  for (int nn = 0; nn < 8; ++nn) {
    const int n = node0 + nn0 + nn;
    if (n < N) {
      Q[(size_t)n * 128 + lane]      = aq[nn][0] * scale;
      Q[(size_t)n * 128 + 64 + lane] = aq[nn][1] * scale;
      KV[(size_t)n * 128 + lane]      = packkv(ak[nn][0], av[nn][0]);
      KV[(size_t)n * 128 + 64 + lane] = packkv(ak[nn][1], av[nn][1]);
    }
  }
}

// ---------------- CSR build ------------------------------------------------
__global__ void count_edges(const int* __restrict__ dst, int* __restrict__ counts, int E) {
  const int e = blockIdx.x * blockDim.x + threadIdx.x;
  if (e < E) atomicAdd(&counts[dst[e]], 1);
}

__global__ __launch_bounds__(1024) void scan_pass1(
    const int* __restrict__ counts, int* __restrict__ offsets,
    int* __restrict__ bsums, int n) {
  __shared__ int tmp[1024];
  const int b = blockIdx.x, tid = threadIdx.x;
  const int i = b * 1024 + tid;
  tmp[tid] = (i < n) ? counts[i] : 0;
  __syncthreads();
  for (int off = 1; off < 1024; off <<= 1) {
    const int t = (tid >= off) ? tmp[tid - off] : 0;
    __syncthreads();
    tmp[tid] += t;
    __syncthreads();
  }
  if (i < n) offsets[i + 1] = tmp[tid];
  if (tid == 1023) bsums[b] = tmp[1023];
}

__global__ void scan_pass2(int* __restrict__ bsums, int nb) {
  const int tid = threadIdx.x;
  int v = (tid < nb) ? bsums[tid] : 0;
#pragma unroll
  for (int off = 1; off < 64; off <<= 1) {
    const int t = __shfl_up(v, off);
    if (tid >= off) v += t;
  }
  if (tid < nb) bsums[tid] = v;
}

__global__ __launch_bounds__(1024) void scan_pass3(
    int* __restrict__ offsets, const int* __restrict__ bsums, int n) {
  const int b = blockIdx.x, tid = threadIdx.x;
  const int i = b * 1024 + tid;
  if (b > 0 && i < n) offsets[i + 1] += bsums[b - 1];
  if (b == 0 && tid == 0) offsets[0] = 0;
}

// cursor pre-loaded with offsets -> atomicAdd returns ABSOLUTE position
__global__ void scatter_edges(const int* __restrict__ dst, const int* __restrict__ src,
                              int* __restrict__ cursor, int* __restrict__ esrc, int E) {
  const int e = blockIdx.x * blockDim.x + threadIdx.x;
  if (e >= E) return;
  const int pos = atomicAdd(&cursor[dst[e]], 1);
  esrc[pos] = src[e];
}

// ---------------- fused per-node attention: 2 nodes/wave, uint4 gathers ----
// 32 lanes per node, 4 feature-pairs per lane; one uint4 (16B) load per lane
// per edge delivers K and V for all 4 owned columns.
__global__ __launch_bounds__(256) void node_attn_kernel(
    const float* __restrict__ Q, const uint32_t* __restrict__ KV,
    const int* __restrict__ offsets, const int* __restrict__ esrc,
    float* __restrict__ out, int N) {
  const int tid = threadIdx.x;
  const int lane = tid & 63;
  const int li = lane & 31;            // lane within node-group
  const int n = blockIdx.x * 8 + (tid >> 5);  // 8 nodes per 256-thr block
  const bool valid = n < N;
  const int nn = valid ? n : 0;
  const int beg = offsets[nn];
  const int end = valid ? offsets[nn + 1] : 0;

  float4 q = *reinterpret_cast<const float4*>(Q + (size_t)nn * 128 + li * 4);  // pre-scaled
  float m = -3.4e38f, l = 0.f, a0 = 0.f, a1 = 0.f, a2 = 0.f, a3 = 0.f;

  int p = beg;
  for (; p + 4 <= end; p += 4) {
    const int s0 = esrc[p], s1 = esrc[p + 1], s2 = esrc[p + 2], s3 = esrc[p + 3];
    const uint4 c0 = *reinterpret_cast<const uint4*>(KV + (size_t)s0 * 128 + li * 4);
    const uint4 c1 = *reinterpret_cast<const uint4*>(KV + (size_t)s1 * 128 + li * 4);
    const uint4 c2 = *reinterpret_cast<const uint4*>(KV + (size_t)s2 * 128 + li * 4);
    const uint4 c3 = *reinterpret_cast<const uint4*>(KV + (size_t)s3 * 128 + li * 4);
    float d0 = q.x * bf2f(c0.x & 0xffff) + q.y * bf2f(c0.y & 0xffff)
             + q.z * bf2f(c0.z & 0xffff) + q.w * bf2f(c0.w & 0xffff);
    float d1 = q.x * bf2f(c1.x & 0xffff) + q.y * bf2f(c1.y & 0xffff)
             + q.z * bf2f(c1.z & 0xffff) + q.w * bf2f(c1.w & 0xffff);
    float d2 = q.x * bf2f(c2.x & 0xffff) + q.y * bf2f(c2.y & 0xffff)
             + q.z * bf2f(c2.z & 0xffff) + q.w * bf2f(c2.w & 0xffff);
    float d3 = q.x * bf2f(c3.x & 0xffff) + q.y * bf2f(c3.y & 0xffff)
             + q.z * bf2f(c3.z & 0xffff) + q.w * bf2f(c3.w & 0xffff);
#pragma unroll
    for (int off = 16; off > 0; off >>= 1) {  // width-32 reduce, stays in group
      d0 += __shfl_xor(d0, off);
      d1 += __shfl_xor(d1, off);
      d2 += __shfl_xor(d2, off);
      d3 += __shfl_xor(d3, off);
    }
    const float mx = fmaxf(fmaxf(d0, d1), fmaxf(d2, d3));
    const float mnew = fmaxf(m, mx);
    const float corr = __expf(m - mnew);
    const float p0 = __expf(d0 - mnew), p1 = __expf(d1 - mnew);
    const float p2 = __expf(d2 - mnew), p3 = __expf(d3 - mnew);
    l = l * corr + (p0 + p1 + p2 + p3);
    a0 = a0 * corr + p0 * bf2f(c0.x >> 16) + p1 * bf2f(c1.x >> 16)
                   + p2 * bf2f(c2.x >> 16) + p3 * bf2f(c3.x >> 16);
    a1 = a1 * corr + p0 * bf2f(c0.y >> 16) + p1 * bf2f(c1.y >> 16)
                   + p2 * bf2f(c2.y >> 16) + p3 * bf2f(c3.y >> 16);
    a2 = a2 * corr + p0 * bf2f(c0.z >> 16) + p1 * bf2f(c1.z >> 16)
                   + p2 * bf2f(c2.z >> 16) + p3 * bf2f(c3.z >> 16);
    a3 = a3 * corr + p0 * bf2f(c0.w >> 16) + p1 * bf2f(c1.w >> 16)
                   + p2 * bf2f(c2.w >> 16) + p3 * bf2f(c3.w >> 16);
    m = mnew;
  }
  for (; p < end; ++p) {  // tail
    const int s = esrc[p];
    const uint4 c = *reinterpret_cast<const uint4*>(KV + (size_t)s * 128 + li * 4);
    float d = q.x * bf2f(c.x & 0xffff) + q.y * bf2f(c.y & 0xffff)
            + q.z * bf2f(c.z & 0xffff) + q.w * bf2f(c.w & 0xffff);
#pragma unroll
    for (int off = 16; off > 0; off >>= 1) d += __shfl_xor(d, off);
    const float mnew = fmaxf(m, d);
    const float corr = __expf(m - mnew);
    const float pe = __expf(d - mnew);
    l = l * corr + pe;
    a0 = a0 * corr + pe * bf2f(c.x >> 16);
    a1 = a1 * corr + pe * bf2f(c.y >> 16);
    a2 = a2 * corr + pe * bf2f(c.z >> 16);
    a3 = a3 * corr + pe * bf2f(c.w >> 16);
    m = mnew;
  }
  if (valid) {
    const float inv = (end > beg) ? 1.f / l : 0.f;
    float4 o; o.x = a0 * inv; o.y = a1 * inv; o.z = a2 * inv; o.w = a3 * inv;
    *reinterpret_cast<float4*>(out + (size_t)n * 128 + li * 4) = o;
  }
}

// ---------------------------------------------------------------------------
extern "C" void kernel_launch(void* const* d_in, const int* in_sizes, int n_in,
                              void* d_out, int out_size, void* d_ws, size_t ws_size,
                              hipStream_t stream) {
  const float* edge_feat = (const float*)d_in[0];
  const float* node_feat = (const float*)d_in[1];
  const int*   src       = (const int*)d_in[2];
  const int*   dst       = (const int*)d_in[3];
  const float* Wq        = (const float*)d_in[4];
  const float* Wk        = (const float*)d_in[5];
  const float* Wv        = (const float*)d_in[6];
  const float* W1        = (const float*)d_in[7];
  const float* b1        = (const float*)d_in[8];
  const float* W2        = (const float*)d_in[9];
  const float* b2        = (const float*)d_in[10];

  const int E = in_sizes[2];            // 800000
  const int N = in_sizes[1] / D_NODE;   // 50000

  float* edge_out = (float*)d_out;
  float* node_out = (float*)d_out + (size_t)E * D_EDGE;

  char* w = (char*)d_ws;
  auto alloc = [&](size_t bytes) {
    char* p = w;
    w += (bytes + 255) & ~(size_t)255;
    return p;
  };
  float*    Q   = (float*)alloc((size_t)N * 128 * sizeof(float));
  uint32_t* KV  = (uint32_t*)alloc((size_t)N * 128 * sizeof(uint32_t));
  int* counts = (int*)alloc((size_t)N * sizeof(int));
  int* cursor = (int*)alloc((size_t)N * sizeof(int));
  int* offs   = (int*)alloc((size_t)(N + 1) * sizeof(int));
  int* esrc   = (int*)alloc((size_t)E * sizeof(int));
  short* W1f  = (short*)alloc(8192 * sizeof(short));
  short* W2f  = (short*)alloc(8192 * sizeof(short));
  int* bsums  = (int*)alloc(64 * sizeof(int));

  hipMemsetAsync(counts, 0, (size_t)N * sizeof(int), stream);

  const int nb = (N + 1023) / 1024;     // 49 blocks
  prep_weights<<<8, 256, 0, stream>>>(W1, W2, W1f, W2f);
  count_edges<<<(E + 255) / 256, 256, 0, stream>>>(dst, counts, E);
  scan_pass1<<<nb, 1024, 0, stream>>>(counts, offs, bsums, N);
  scan_pass2<<<1, 64, 0, stream>>>(bsums, nb);
  scan_pass3<<<nb, 1024, 0, stream>>>(offs, bsums, N);
  hipMemcpyAsync(cursor, offs, (size_t)N * sizeof(int), hipMemcpyDeviceToDevice, stream);
  scatter_edges<<<(E + 255) / 256, 256, 0, stream>>>(dst, src, cursor, esrc, E);
  qkv_kernel<<<(N + 31) / 32, 256, 0, stream>>>(node_feat, Wq, Wk, Wv, Q, KV, N);
  edge_mlp_mfma<<<(E + 127) / 128, 256, 0, stream>>>(edge_feat, W1f, b1, W2f, b2, edge_out, E);
  node_attn_kernel<<<(N + 7) / 8, 256, 0, stream>>>(Q, KV, offs, esrc, node_out, N);
}